// Round 6
// baseline (1622.492 us; speedup 1.0000x reference)
//
#include <hip/hip_runtime.h>

// textPCNN fused (R11): R10 falsified the B-L2-bandwidth theory (halving B
// traffic regressed 180->191; 2-block phase independence matters more).
// Remaining gap (180 vs 78.6us MFMA floor, all pipes ~40%): load-issue
// BUNCHING — R9 issues 4 B-prefetches + 4 A-reads as one burst per cluster,
// 16 lockstep waves/CU -> 64KB L2 demand in ~200cy, ~1100cy return
// serialization with MFMA idle, then MFMA burst with L2 idle (pipes
// anti-correlated). Fix: revert to R9 structure, weave each b_next[jt] load
// between MFMA groups (1 load : 4 MFMAs) and drop the s_setprio fences so
// the scheduler may intermix. Regs unchanged (acc64+b32+a16 ~ 124 <= 128).

#define XSTRIDE 424     // LDS x-row stride in bf16 elems (848 B = 53 short8)
#define LPV 126
#define NC 53

typedef __attribute__((ext_vector_type(8))) short short8;
typedef __attribute__((ext_vector_type(4))) float floatx4;

__device__ __forceinline__ unsigned short f2bf_rne(float x) {
    unsigned u = __float_as_uint(x);
    u += 0x7fffu + ((u >> 16) & 1u);   // round-to-nearest-even (inputs finite)
    return (unsigned short)(u >> 16);
}

// prep: conv_w fp32 [512][3*400] -> bf16 frag-packed convwb2:
//   flat = (((ftile*38+ks)*4+kq)*16+col)*8 + e ; k=ks*32+kq*8+e, f=ftile*16+col
//   k>=1200 -> 0 (zero K tail, uniform 38-iter K-loop)
// plus out_w [1536][53] -> outwT [53][1536] fp32 (coalesced epilogue reads).
__global__ void __launch_bounds__(1024)
prep(const float* __restrict__ convw, const float* __restrict__ outw,
     unsigned short* __restrict__ convwb2, float* __restrict__ outwT) {
    int i = blockIdx.x * 1024 + threadIdx.x;
    if (i < 622592) {
        int e = i & 7, col = (i >> 3) & 15, kq = (i >> 7) & 3;
        int rest = i >> 9;
        int ks = rest % 38, ftile = rest / 38;
        int k = ks * 32 + kq * 8 + e, f = ftile * 16 + col;
        convwb2[i] = (k < 1200) ? f2bf_rne(convw[f * 1200 + k])
                                : (unsigned short)0;
    } else {
        int i2 = i - 622592;
        if (i2 < 81408) {                  // 53*1536
            int c = i2 / 1536, j = i2 - c * 1536;
            outwT[i2] = outw[j * 53 + c];
        }
    }
}

// kernel 2: one block per (sentence, t-half). Gather 67 x-rows -> LDS,
// conv GEMM 8 waves x (64t x 64f) with load-interleaved register-dbuf B,
// pool raw 3-seg max, write to ws pfe.
extern "C" __global__ void __launch_bounds__(512, 4)
pcnn_half(const int* __restrict__ tokens, const int* __restrict__ pf1,
          const int* __restrict__ pf2, const int* __restrict__ epos,
          const float* __restrict__ wordvec,
          const float* __restrict__ pf1e,
          const float* __restrict__ pf2e,
          const unsigned short* __restrict__ convwb2,  // frag-packed bf16 in ws
          float* __restrict__ pfe)                     // [1024][2][1536] raw max
{
    extern __shared__ char smem[];
    unsigned short* xl = (unsigned short*)smem;        // 67*424 ush = 56816 B
    int* idx = (int*)(smem + 56816);                   // 3*67 ints (816 B pad)

    const int bid = blockIdx.x;
    const int n   = bid >> 1;
    const int wr  = bid & 1;        // t-half: global t in [64wr, 64wr+64)
    const int r0  = wr * 64;
    const int nreal = wr ? 64 : 67; // real x-rows this block stages

    const int tid  = threadIdx.x;
    const int lane = tid & 63;
    const int wv   = tid >> 6;      // 0..7 : f in [64wv, 64wv+64)

    if (tid < nreal) {
        int base = n * 128 + r0 + tid;
        idx[tid]       = tokens[base];
        idx[67 + tid]  = pf1[base];
        idx[134 + tid] = pf2[base];
    }
    if (wr) {   // local rows 64..66 are past end of sentence: zero them
        const short8 z8 = {0, 0, 0, 0, 0, 0, 0, 0};
        short8* dst = (short8*)xl;                     // 53 short8 per row
        for (int i = tid; i < 159; i += 512) {
            int row = 64 + i / 53, c = i % 53;
            dst[row * 53 + c] = z8;
        }
    }
    __syncthreads();

    // ---- gather + fp32->bf16 (float4 word loads; rows 16B-aligned) ----
    {
        const float4* wv4 = (const float4*)wordvec;    // 75 float4 per row
        const float2* p12 = (const float2*)pf1e;       // 25 float2 per row
        const float2* p22 = (const float2*)pf2e;
        #pragma unroll 4
        for (int i = tid; i < nreal * 75; i += 512) {  // word part
            int row = i / 75, c = i - row * 75;
            float4 v = wv4[(long)idx[row] * 75 + c];
            *(ushort4*)(xl + row * XSTRIDE + 4 * c) =
                make_ushort4(f2bf_rne(v.x), f2bf_rne(v.y),
                             f2bf_rne(v.z), f2bf_rne(v.w));
        }
        #pragma unroll 4
        for (int i = tid; i < nreal * 25; i += 512) {  // pf1 + pf2 parts
            int row = i / 25, c = i - row * 25;
            float2 v = p12[idx[67 + row] * 25 + c];
            *(ushort2*)(xl + row * XSTRIDE + 300 + 2 * c) =
                make_ushort2(f2bf_rne(v.x), f2bf_rne(v.y));
            float2 w = p22[idx[134 + row] * 25 + c];
            *(ushort2*)(xl + row * XSTRIDE + 350 + 2 * c) =
                make_ushort2(f2bf_rne(w.x), f2bf_rne(w.y));
        }
    }
    __syncthreads();

    // ---- conv GEMM: wave wv owns local t[0,64) x f[64wv, 64wv+64) ----
    // A[t][k] = xl[t + k/400][k%400]; B frag-packed (1KB coalesced wave-loads),
    // register-double-buffered one K-step ahead, loads WOVEN between MFMA
    // groups (1 load : 4 MFMAs) to spread L2 demand across the MFMA window.
    const int col = lane & 15;   // A row-in-tile / B f-in-tile / C col
    const int kq  = lane >> 4;   // k-quad: k offset 8*kq; C row = 4*kq + r

    const floatx4 fz = {0.f, 0.f, 0.f, 0.f};
    floatx4 acc[4][4];   // [mt][jt]
    #pragma unroll
    for (int mt = 0; mt < 4; ++mt)
        #pragma unroll
        for (int jt = 0; jt < 4; ++jt) acc[mt][jt] = fz;

    int ck   = kq * 8;                           // k mod 400 for this lane
    int aoff = col * XSTRIDE + kq * 8;
    const unsigned short* bwv = convwb2 + (wv * 4 * 38) * 512 + lane * 8;

    short8 b0[4], b1[4];
    #pragma unroll
    for (int jt = 0; jt < 4; ++jt)               // prologue: ks=0
        b0[jt] = *(const short8*)(bwv + (jt * 38) * 512);

    #pragma unroll 1
    for (int ks = 0; ks < 38; ks += 2) {         // 19 iterations, 2 K-steps each
        short8 a[4];
        // ---- half A: consume b0 (ks), prefetch b1 (ks+1) woven per-jt ----
        #pragma unroll
        for (int mt = 0; mt < 4; ++mt)
            a[mt] = *(const short8*)(xl + aoff + mt * (16 * XSTRIDE));
        #pragma unroll
        for (int jt = 0; jt < 4; ++jt) {
            b1[jt] = *(const short8*)(bwv + (jt * 38 + ks + 1) * 512);
            #pragma unroll
            for (int mt = 0; mt < 4; ++mt)
                acc[mt][jt] = __builtin_amdgcn_mfma_f32_16x16x32_bf16(
                    a[mt], b0[jt], acc[mt][jt], 0, 0, 0);
        }
        ck += 32; aoff += 32;
        if (ck >= 400) { ck -= 400; aoff += XSTRIDE - 400; }

        // ---- half B: consume b1 (ks+1), prefetch b0 (ks+2, guarded) ----
        #pragma unroll
        for (int mt = 0; mt < 4; ++mt)
            a[mt] = *(const short8*)(xl + aoff + mt * (16 * XSTRIDE));
        if (ks + 2 < 38) {
            #pragma unroll
            for (int jt = 0; jt < 4; ++jt) {
                b0[jt] = *(const short8*)(bwv + (jt * 38 + ks + 2) * 512);
                #pragma unroll
                for (int mt = 0; mt < 4; ++mt)
                    acc[mt][jt] = __builtin_amdgcn_mfma_f32_16x16x32_bf16(
                        a[mt], b1[jt], acc[mt][jt], 0, 0, 0);
            }
        } else {
            #pragma unroll
            for (int jt = 0; jt < 4; ++jt)
                #pragma unroll
                for (int mt = 0; mt < 4; ++mt)
                    acc[mt][jt] = __builtin_amdgcn_mfma_f32_16x16x32_bf16(
                        a[mt], b1[jt], acc[mt][jt], 0, 0, 0);
        }
        ck += 32; aoff += 32;
        if (ck >= 400) { ck -= 400; aoff += XSTRIDE - 400; }
    }

    // ---- pool raw acc over 3 segments (this half's t-range), write ws ----
    const int p1 = epos[2 * n], p2 = epos[2 * n + 1];
    float* pf_out = pfe + (n * 2 + wr) * 1536;
    #pragma unroll
    for (int jt = 0; jt < 4; ++jt) {
        float m0 = -1e30f, m1 = -1e30f, m2 = -1e30f;
        #pragma unroll
        for (int mt = 0; mt < 4; ++mt) {
            #pragma unroll
            for (int r = 0; r < 4; ++r) {
                int gt = r0 + mt * 16 + kq * 4 + r;   // global t (C/D row map)
                float v = acc[mt][jt][r];
                if (gt < LPV) {
                    if (gt <= p1) m0 = fmaxf(m0, v);
                    if (gt >= p1 && gt <= p2) m1 = fmaxf(m1, v);
                    if (gt >= p2) m2 = fmaxf(m2, v);
                }
            }
        }
        // lanes sharing col differ in kq (xor 16, 32): reduce t-coverage
        m0 = fmaxf(m0, __shfl_xor(m0, 16)); m0 = fmaxf(m0, __shfl_xor(m0, 32));
        m1 = fmaxf(m1, __shfl_xor(m1, 16)); m1 = fmaxf(m1, __shfl_xor(m1, 32));
        m2 = fmaxf(m2, __shfl_xor(m2, 16)); m2 = fmaxf(m2, __shfl_xor(m2, 32));
        if (kq == 0) {
            int f = wv * 64 + jt * 16 + col;
            pf_out[3 * f + 0] = m0;    // raw max; tanh after cross-half combine
            pf_out[3 * f + 1] = m1;
            pf_out[3 * f + 2] = m2;
        }
    }
}

// kernel 3: combine t-halves, +bias, tanh, out GEMM. One block per sentence.
// (1024 blocks keeps grid saturated; outwT L2 re-reads ~10us aggregate.)
extern "C" __global__ void __launch_bounds__(256)
pcnn_out(const float* __restrict__ pfe, const float* __restrict__ convb,
         const float* __restrict__ outwT,            // [53][1536] fp32 in ws
         const float* __restrict__ outb, float* __restrict__ out)
{
    __shared__ float feat[1536];
    const int n = blockIdx.x;
    const int tid = threadIdx.x;
    const float* pa = pfe + n * 3072;
    const float* pb = pa + 1536;

    for (int i = tid; i < 1536; i += 256) {
        float v = fmaxf(pa[i], pb[i]);
        // tanh monotonic: max(tanh(x+b)) == tanh(max(x)+b); segs nonempty
        feat[i] = tanhf(v + convb[i / 3]);
    }
    __syncthreads();

    const int lane = tid & 63;
    const int wv   = tid >> 6;     // 0..3
    for (int cc = wv; cc < NC; cc += 4) {
        const float* wrow = outwT + cc * 1536;
        float s = 0.f;
        #pragma unroll 4
        for (int jj = lane; jj < 1536; jj += 64)
            s += feat[jj] * wrow[jj];
        s += __shfl_xor(s, 32); s += __shfl_xor(s, 16);
        s += __shfl_xor(s, 8);  s += __shfl_xor(s, 4);
        s += __shfl_xor(s, 2);  s += __shfl_xor(s, 1);
        if (lane == 0) out[n * 53 + cc] = s + outb[cc];
    }
}

extern "C" void kernel_launch(void* const* d_in, const int* in_sizes, int n_in,
                              void* d_out, int out_size, void* d_ws, size_t ws_size,
                              hipStream_t stream) {
    (void)in_sizes; (void)n_in; (void)ws_size; (void)out_size;
    const int* tokens = (const int*)d_in[0];
    const int* pf1    = (const int*)d_in[1];
    const int* pf2    = (const int*)d_in[2];
    const int* epos   = (const int*)d_in[3];
    const float* wordvec = (const float*)d_in[4];
    const float* pf1e    = (const float*)d_in[5];
    const float* pf2e    = (const float*)d_in[6];
    const float* convw   = (const float*)d_in[7];
    const float* convb   = (const float*)d_in[8];
    const float* outw    = (const float*)d_in[9];
    const float* outb    = (const float*)d_in[10];
    float* out = (float*)d_out;

    unsigned short* convwb2 = (unsigned short*)d_ws;       // 1,245,184 B
    float* outwT = (float*)((char*)d_ws + 1245184);        // 325,632 B
    float* pfe   = (float*)((char*)d_ws + 1570816);        // 1024*2*1536 f = 12.6 MB

    prep<<<dim3(688), dim3(1024), 0, stream>>>(convw, outw, convwb2, outwT);

    const size_t lds_bytes = 56816 + 816;                  // 57,632 B -> 2 blocks/CU
    pcnn_half<<<dim3(2048), dim3(512), lds_bytes, stream>>>(
        tokens, pf1, pf2, epos, wordvec, pf1e, pf2e, convwb2, pfe);

    pcnn_out<<<dim3(1024), dim3(256), 0, stream>>>(pfe, convb, outwT, outb, out);
}

// Round 7
// 412.930 us; speedup vs baseline: 3.9292x; 3.9292x over previous
//
#include <hip/hip_runtime.h>

// textPCNN fused (R12): R11 spilled acc (WRITE_SIZE 4.7GB = scratch) — weave
// reverted. Recomputed floors at R9=180us: MFMA 78.6us, B-from-L2 67us/CU
// (9.7MB @ ~60B/cy) — co-equal, barely overlapping. Fix: merged per-sentence
// block (16 waves), B staged through LDS via global_load_lds (T3-minimal,
// 2-barrier single-buffer K-loop): B-L2 halves to 5MB/CU, stage lands async
// under the 1241cy/step MFMA window, B reads become conflict-free linear
// ds_read_b128. XSTRIDE 424->408 to fit LDS (A 106.9K + stage 32K + idx =
// 141.2K, 1 blk/CU). Epilogue fused in-block (pfeat aliases dead stage buf):
// no 3rd kernel, no 12.6MB pfe round-trip. stage(0) drains on gather barrier.

#define XSTRIDE 408     // LDS A-row stride in bf16 elems (816 B = 51 short8)
#define XL_BYTES 106896 // 131 rows * 408 * 2
#define BST_OFF  106896 // B stage buffer: 32768 B (aliased by pfeat after loop)
#define IDX_OFF  139664 // 3*128 ints = 1536 B ; total LDS = 141200
#define LPV 126
#define NC 53

typedef __attribute__((ext_vector_type(8))) short short8;
typedef __attribute__((ext_vector_type(4))) float floatx4;

__device__ __forceinline__ unsigned short f2bf_rne(float x) {
    unsigned u = __float_as_uint(x);
    u += 0x7fffu + ((u >> 16) & 1u);   // round-to-nearest-even (inputs finite)
    return (unsigned short)(u >> 16);
}

__device__ __forceinline__ void gload_lds16(const void* g, void* l) {
    __builtin_amdgcn_global_load_lds(
        (const __attribute__((address_space(1))) void*)g,
        (__attribute__((address_space(3))) void*)l, 16, 0, 0);
}

// prep: conv_w fp32 [512][3*400] -> bf16 K-step-major frag pack convwb3:
//   i = ks*16384 + sl*512 + (kq*16+col)*8 + e ; k=ks*32+kq*8+e, f=sl*16+col
//   (per-ks 32KB contiguous slab -> whole-block LDS stage is 32 linear 1KB
//    wave-loads; lane==kq*16+col so ds_read addr = sl*512+lane*8, linear.)
//   k>=1200 -> 0 (zero K tail, uniform 38-iter K-loop)
// plus out_w [1536][53] -> outwT [53][1536] fp32 (coalesced epilogue reads).
__global__ void __launch_bounds__(1024)
prep(const float* __restrict__ convw, const float* __restrict__ outw,
     unsigned short* __restrict__ convwb3, float* __restrict__ outwT) {
    int i = blockIdx.x * 1024 + threadIdx.x;
    if (i < 622592) {
        int ks = i >> 14;
        int r  = i & 16383;
        int sl = r >> 9;
        int q  = r & 511;
        int kq = q >> 7, col = (q >> 3) & 15, e = q & 7;
        int k = ks * 32 + kq * 8 + e, f = sl * 16 + col;
        convwb3[i] = (k < 1200) ? f2bf_rne(convw[f * 1200 + k])
                                : (unsigned short)0;
    } else {
        int i2 = i - 622592;
        if (i2 < 81408) {                  // 53*1536
            int c = i2 / 1536, j = i2 - c * 1536;
            outwT[i2] = outw[j * 53 + c];
        }
    }
}

// kernel 2: one block per sentence, 16 waves (2 t-halves x 8 f-slices).
// Gather -> LDS A; K-loop: ds_read A,B frags | barrier | async-stage next B
// slab | MFMA | vmcnt(0) barrier; fused pool + tanh + out GEMM epilogue.
extern "C" __global__ void __launch_bounds__(1024, 4)
pcnn_conv(const int* __restrict__ tokens, const int* __restrict__ pf1,
          const int* __restrict__ pf2, const int* __restrict__ epos,
          const float* __restrict__ wordvec,
          const float* __restrict__ pf1e,
          const float* __restrict__ pf2e,
          const unsigned short* __restrict__ convwb3,  // K-step-major bf16 ws
          const float* __restrict__ convb,
          const float* __restrict__ outwT,             // [53][1536] fp32 ws
          const float* __restrict__ outb,
          float* __restrict__ out)
{
    extern __shared__ char smem[];
    unsigned short* xl  = (unsigned short*)smem;            // A tile
    unsigned short* bst = (unsigned short*)(smem + BST_OFF);// B stage (32KB)
    float* pfeat        = (float*)(smem + BST_OFF);         // aliases bst
    int*   idx          = (int*)(smem + IDX_OFF);

    const int n    = blockIdx.x;
    const int tid  = threadIdx.x;
    const int lane = tid & 63;
    const int wv   = tid >> 6;      // 0..15
    const int wvf  = wv & 7;        // f-slice: f in [64wvf, +64)
    const int wr   = wv >> 3;       // t-half: t in [64wr, +64)
    const int r0   = wr * 64;

    // ---- issue stage(ks=0) immediately; gather's __syncthreads drains it ----
    {
        const unsigned short* g0 = convwb3 + (2 * wv) * 512 + lane * 8;
        gload_lds16(g0,       bst + (2 * wv) * 512);
        gload_lds16(g0 + 512, bst + (2 * wv + 1) * 512);
    }

    if (tid < 128) {
        int base = n * 128 + tid;
        idx[tid]       = tokens[base];
        idx[128 + tid] = pf1[base];
        idx[256 + tid] = pf2[base];
    }
    {   // zero rows 128..130 (t=126..127 windows + zero-K-tail row reads)
        const short8 z8 = {0, 0, 0, 0, 0, 0, 0, 0};
        short8* dst = (short8*)xl;                     // 51 short8 per row
        for (int i = tid; i < 153; i += 1024) {
            int row = 128 + i / 51, c = i % 51;
            dst[row * 51 + c] = z8;
        }
    }
    __syncthreads();

    // ---- gather + fp32->bf16 (float4 word loads; rows 16B-aligned) ----
    {
        const float4* wv4 = (const float4*)wordvec;    // 75 float4 per row
        const float2* p12 = (const float2*)pf1e;       // 25 float2 per row
        const float2* p22 = (const float2*)pf2e;
        #pragma unroll 4
        for (int i = tid; i < 128 * 75; i += 1024) {   // word part
            int row = i / 75, c = i - row * 75;
            float4 v = wv4[(long)idx[row] * 75 + c];
            *(ushort4*)(xl + row * XSTRIDE + 4 * c) =
                make_ushort4(f2bf_rne(v.x), f2bf_rne(v.y),
                             f2bf_rne(v.z), f2bf_rne(v.w));
        }
        #pragma unroll 4
        for (int i = tid; i < 128 * 25; i += 1024) {   // pf1 + pf2 parts
            int row = i / 25, c = i - row * 25;
            float2 v = p12[idx[128 + row] * 25 + c];
            *(ushort2*)(xl + row * XSTRIDE + 300 + 2 * c) =
                make_ushort2(f2bf_rne(v.x), f2bf_rne(v.y));
            float2 w = p22[idx[256 + row] * 25 + c];
            *(ushort2*)(xl + row * XSTRIDE + 350 + 2 * c) =
                make_ushort2(f2bf_rne(w.x), f2bf_rne(w.y));
        }
    }
    __syncthreads();    // compiler drains vmcnt(0) here -> stage(0) complete

    // ---- conv GEMM: wave owns t[64wr,+64) x f[64wvf,+64) ----
    const int col = lane & 15;   // A row-in-tile / B f-in-tile / C col
    const int kq  = lane >> 4;   // k-quad: k offset 8*kq; C row = 4*kq + r

    const floatx4 fz = {0.f, 0.f, 0.f, 0.f};
    floatx4 acc[4][4];   // [mt][jt]
    #pragma unroll
    for (int mt = 0; mt < 4; ++mt)
        #pragma unroll
        for (int jt = 0; jt < 4; ++jt) acc[mt][jt] = fz;

    int ck   = kq * 8;                           // k mod 400 for this lane
    int aoff = (r0 + col) * XSTRIDE + kq * 8;
    const unsigned short* brd = bst + (wvf * 4) * 512 + lane * 8;
    unsigned short* l0 = bst + (2 * wv) * 512;   // my wave's stage dests
    unsigned short* l1 = l0 + 512;

    #pragma unroll 1
    for (int ks = 0; ks < 38; ++ks) {
        short8 b[4], a[4];
        #pragma unroll
        for (int jt = 0; jt < 4; ++jt)
            b[jt] = *(const short8*)(brd + jt * 512);
        #pragma unroll
        for (int mt = 0; mt < 4; ++mt)
            a[mt] = *(const short8*)(xl + aoff + mt * (16 * XSTRIDE));
        // my LDS reads landed in regs; then block-wide "reads done" barrier
        asm volatile("s_waitcnt lgkmcnt(0)" ::: "memory");
        __builtin_amdgcn_sched_barrier(0);
        __builtin_amdgcn_s_barrier();            // barrier1
        __builtin_amdgcn_sched_barrier(0);
        // async-stage next K-slab (last iter: restage 37, lands unread)
        {
            int ksn = (ks < 37) ? ks + 1 : 37;
            const unsigned short* g0 =
                convwb3 + ksn * 16384 + (2 * wv) * 512 + lane * 8;
            gload_lds16(g0,       l0);
            gload_lds16(g0 + 512, l1);
        }
        __builtin_amdgcn_s_setprio(1);
        #pragma unroll
        for (int mt = 0; mt < 4; ++mt)
            #pragma unroll
            for (int jt = 0; jt < 4; ++jt)
                acc[mt][jt] = __builtin_amdgcn_mfma_f32_16x16x32_bf16(
                    a[mt], b[jt], acc[mt][jt], 0, 0, 0);
        __builtin_amdgcn_s_setprio(0);
        // my stage writes landed; block-wide "stage done" barrier
        asm volatile("s_waitcnt vmcnt(0)" ::: "memory");
        __builtin_amdgcn_sched_barrier(0);
        __builtin_amdgcn_s_barrier();            // barrier2
        __builtin_amdgcn_sched_barrier(0);
        ck += 32; aoff += 32;
        if (ck >= 400) { ck -= 400; aoff += XSTRIDE - 400; }
    }

    // ---- pool raw acc over 3 segments (this half's t-range) -> pfeat ----
    const int p1 = epos[2 * n], p2 = epos[2 * n + 1];
    #pragma unroll
    for (int jt = 0; jt < 4; ++jt) {
        float m0 = -1e30f, m1 = -1e30f, m2 = -1e30f;
        #pragma unroll
        for (int mt = 0; mt < 4; ++mt) {
            #pragma unroll
            for (int r = 0; r < 4; ++r) {
                int gt = r0 + mt * 16 + kq * 4 + r;   // global t (C/D row map)
                float v = acc[mt][jt][r];
                if (gt < LPV) {
                    if (gt <= p1) m0 = fmaxf(m0, v);
                    if (gt >= p1 && gt <= p2) m1 = fmaxf(m1, v);
                    if (gt >= p2) m2 = fmaxf(m2, v);
                }
            }
        }
        // lanes sharing col differ in kq (xor 16, 32): reduce t-coverage
        m0 = fmaxf(m0, __shfl_xor(m0, 16)); m0 = fmaxf(m0, __shfl_xor(m0, 32));
        m1 = fmaxf(m1, __shfl_xor(m1, 16)); m1 = fmaxf(m1, __shfl_xor(m1, 32));
        m2 = fmaxf(m2, __shfl_xor(m2, 16)); m2 = fmaxf(m2, __shfl_xor(m2, 32));
        if (kq == 0) {
            int f = wvf * 64 + jt * 16 + col;
            pfeat[wr * 1536 + 3 * f + 0] = m0;   // raw max (bst is dead now)
            pfeat[wr * 1536 + 3 * f + 1] = m1;
            pfeat[wr * 1536 + 3 * f + 2] = m2;
        }
    }
    __syncthreads();

    // ---- combine t-halves, +bias, tanh (monotonic: tanh(max+b)) ----
    for (int i = tid; i < 1536; i += 1024) {
        float v = fmaxf(pfeat[i], pfeat[1536 + i]);
        pfeat[i] = tanhf(v + convb[i / 3]);      // in place -> feat
    }
    __syncthreads();

    // ---- out GEMM: coalesced outwT rows, lanes stride j, shuffle reduce ----
    {
        const float* feat = pfeat;
        for (int cc = wv; cc < NC; cc += 16) {
            const float* wrow = outwT + cc * 1536;
            float s = 0.f;
            #pragma unroll 4
            for (int jj = lane; jj < 1536; jj += 64)
                s += feat[jj] * wrow[jj];
            s += __shfl_xor(s, 32); s += __shfl_xor(s, 16);
            s += __shfl_xor(s, 8);  s += __shfl_xor(s, 4);
            s += __shfl_xor(s, 2);  s += __shfl_xor(s, 1);
            if (lane == 0) out[n * 53 + cc] = s + outb[cc];
        }
    }
}

extern "C" void kernel_launch(void* const* d_in, const int* in_sizes, int n_in,
                              void* d_out, int out_size, void* d_ws, size_t ws_size,
                              hipStream_t stream) {
    (void)in_sizes; (void)n_in; (void)ws_size; (void)out_size;
    const int* tokens = (const int*)d_in[0];
    const int* pf1    = (const int*)d_in[1];
    const int* pf2    = (const int*)d_in[2];
    const int* epos   = (const int*)d_in[3];
    const float* wordvec = (const float*)d_in[4];
    const float* pf1e    = (const float*)d_in[5];
    const float* pf2e    = (const float*)d_in[6];
    const float* convw   = (const float*)d_in[7];
    const float* convb   = (const float*)d_in[8];
    const float* outw    = (const float*)d_in[9];
    const float* outb    = (const float*)d_in[10];
    float* out = (float*)d_out;

    unsigned short* convwb3 = (unsigned short*)d_ws;       // 1,245,184 B
    float* outwT = (float*)((char*)d_ws + 1245184);        // 325,632 B

    prep<<<dim3(688), dim3(1024), 0, stream>>>(convw, outw, convwb3, outwT);

    const size_t lds_bytes = 141200;                       // 1 block/CU
    pcnn_conv<<<dim3(1024), dim3(1024), lds_bytes, stream>>>(
        tokens, pf1, pf2, epos, wordvec, pf1e, pf2e, convwb3,
        convb, outwT, outb, out);
}

// Round 8
// 358.514 us; speedup vs baseline: 4.5256x; 1.1518x over previous
//
#include <hip/hip_runtime.h>

// textPCNN fused (R13): R12 confirmed 2-barrier LDS staging puts stage+drain
// on the critical path (m233 pattern; 278us). Constant across R9-R12:
// MfmaUtil == 78.6us/dur — only exposed non-MFMA time varies. R9's 101us
// exposure = B-load waits hit by all 4 waves/SIMD SIMULTANEOUSLY (lockstep
// from gather barrier; identical cadence). Per-SIMD math: each wave has
// ~930cy of SIMD-mate MFMA to hide its ~500cy L2 wait — iff waves are
// time-offset. R8's k-rotation changed addresses not timing; R9>R10 shows
// natural 2-block phase drift already helps. Fix: s_sleep stagger
// (0/320/640/960cy by wv&3) after the gather barrier. Else byte-identical R9.

#define XSTRIDE 424     // LDS x-row stride in bf16 elems (848 B = 53 short8)
#define LPV 126
#define NC 53

typedef __attribute__((ext_vector_type(8))) short short8;
typedef __attribute__((ext_vector_type(4))) float floatx4;

__device__ __forceinline__ unsigned short f2bf_rne(float x) {
    unsigned u = __float_as_uint(x);
    u += 0x7fffu + ((u >> 16) & 1u);   // round-to-nearest-even (inputs finite)
    return (unsigned short)(u >> 16);
}

// prep: conv_w fp32 [512][3*400] -> bf16 frag-packed convwb2:
//   flat = (((ftile*38+ks)*4+kq)*16+col)*8 + e ; k=ks*32+kq*8+e, f=ftile*16+col
//   k>=1200 -> 0 (zero K tail, uniform 38-iter K-loop)
// plus out_w [1536][53] -> outwT [53][1536] fp32 (coalesced epilogue reads).
__global__ void __launch_bounds__(1024)
prep(const float* __restrict__ convw, const float* __restrict__ outw,
     unsigned short* __restrict__ convwb2, float* __restrict__ outwT) {
    int i = blockIdx.x * 1024 + threadIdx.x;
    if (i < 622592) {
        int e = i & 7, col = (i >> 3) & 15, kq = (i >> 7) & 3;
        int rest = i >> 9;
        int ks = rest % 38, ftile = rest / 38;
        int k = ks * 32 + kq * 8 + e, f = ftile * 16 + col;
        convwb2[i] = (k < 1200) ? f2bf_rne(convw[f * 1200 + k])
                                : (unsigned short)0;
    } else {
        int i2 = i - 622592;
        if (i2 < 81408) {                  // 53*1536
            int c = i2 / 1536, j = i2 - c * 1536;
            outwT[i2] = outw[j * 53 + c];
        }
    }
}

// kernel 2: one block per (sentence, t-half). Gather 67 x-rows -> LDS,
// conv GEMM 8 waves x (64t x 64f) with register-double-buffered B and
// time-staggered wave starts, pool raw 3-seg max, write to ws pfe.
extern "C" __global__ void __launch_bounds__(512, 4)
pcnn_half(const int* __restrict__ tokens, const int* __restrict__ pf1,
          const int* __restrict__ pf2, const int* __restrict__ epos,
          const float* __restrict__ wordvec,
          const float* __restrict__ pf1e,
          const float* __restrict__ pf2e,
          const unsigned short* __restrict__ convwb2,  // frag-packed bf16 in ws
          float* __restrict__ pfe)                     // [1024][2][1536] raw max
{
    extern __shared__ char smem[];
    unsigned short* xl = (unsigned short*)smem;        // 67*424 ush = 56816 B
    int* idx = (int*)(smem + 56816);                   // 3*67 ints (816 B pad)

    const int bid = blockIdx.x;
    const int n   = bid >> 1;
    const int wr  = bid & 1;        // t-half: global t in [64wr, 64wr+64)
    const int r0  = wr * 64;
    const int nreal = wr ? 64 : 67; // real x-rows this block stages

    const int tid  = threadIdx.x;
    const int lane = tid & 63;
    const int wv   = tid >> 6;      // 0..7 : f in [64wv, 64wv+64)

    if (tid < nreal) {
        int base = n * 128 + r0 + tid;
        idx[tid]       = tokens[base];
        idx[67 + tid]  = pf1[base];
        idx[134 + tid] = pf2[base];
    }
    if (wr) {   // local rows 64..66 are past end of sentence: zero them
        const short8 z8 = {0, 0, 0, 0, 0, 0, 0, 0};
        short8* dst = (short8*)xl;                     // 53 short8 per row
        for (int i = tid; i < 159; i += 512) {
            int row = 64 + i / 53, c = i % 53;
            dst[row * 53 + c] = z8;
        }
    }
    __syncthreads();

    // ---- gather + fp32->bf16 (float4 word loads; rows 16B-aligned) ----
    {
        const float4* wv4 = (const float4*)wordvec;    // 75 float4 per row
        const float2* p12 = (const float2*)pf1e;       // 25 float2 per row
        const float2* p22 = (const float2*)pf2e;
        #pragma unroll 4
        for (int i = tid; i < nreal * 75; i += 512) {  // word part
            int row = i / 75, c = i - row * 75;
            float4 v = wv4[(long)idx[row] * 75 + c];
            *(ushort4*)(xl + row * XSTRIDE + 4 * c) =
                make_ushort4(f2bf_rne(v.x), f2bf_rne(v.y),
                             f2bf_rne(v.z), f2bf_rne(v.w));
        }
        #pragma unroll 4
        for (int i = tid; i < nreal * 25; i += 512) {  // pf1 + pf2 parts
            int row = i / 25, c = i - row * 25;
            float2 v = p12[idx[67 + row] * 25 + c];
            *(ushort2*)(xl + row * XSTRIDE + 300 + 2 * c) =
                make_ushort2(f2bf_rne(v.x), f2bf_rne(v.y));
            float2 w = p22[idx[134 + row] * 25 + c];
            *(ushort2*)(xl + row * XSTRIDE + 350 + 2 * c) =
                make_ushort2(f2bf_rne(w.x), f2bf_rne(w.y));
        }
    }
    __syncthreads();

    // ---- time-stagger SIMD-mate waves (~320cy steps): one wave's L2 wait
    // then overlaps its mates' MFMA windows; offsets self-sustain via issue
    // arbitration. Re-convergence cost <= 960cy (~0.4us) at epilogue.
    switch (wv & 3) {
        case 1: __builtin_amdgcn_s_sleep(5);  break;
        case 2: __builtin_amdgcn_s_sleep(10); break;
        case 3: __builtin_amdgcn_s_sleep(15); break;
        default: break;
    }

    // ---- conv GEMM: wave wv owns local t[0,64) x f[64wv, 64wv+64) ----
    // A[t][k] = xl[t + k/400][k%400]; B frag-packed (1KB coalesced wave-loads),
    // register-double-buffered one K-step ahead (unroll-2, no copies).
    const int col = lane & 15;   // A row-in-tile / B f-in-tile / C col
    const int kq  = lane >> 4;   // k-quad: k offset 8*kq; C row = 4*kq + r

    const floatx4 fz = {0.f, 0.f, 0.f, 0.f};
    floatx4 acc[4][4];   // [mt][jt]
    #pragma unroll
    for (int mt = 0; mt < 4; ++mt)
        #pragma unroll
        for (int jt = 0; jt < 4; ++jt) acc[mt][jt] = fz;

    int ck   = kq * 8;                           // k mod 400 for this lane
    int aoff = col * XSTRIDE + kq * 8;
    const unsigned short* bwv = convwb2 + (wv * 4 * 38) * 512 + lane * 8;

    short8 b0[4], b1[4];
    #pragma unroll
    for (int jt = 0; jt < 4; ++jt)               // prologue: ks=0
        b0[jt] = *(const short8*)(bwv + (jt * 38) * 512);

    #pragma unroll 1
    for (int ks = 0; ks < 38; ks += 2) {         // 19 iterations, 2 K-steps each
        short8 a[4];
        // prefetch ks+1 into b1 (always valid: ks+1 <= 37)
        #pragma unroll
        for (int jt = 0; jt < 4; ++jt)
            b1[jt] = *(const short8*)(bwv + (jt * 38 + ks + 1) * 512);
        #pragma unroll
        for (int mt = 0; mt < 4; ++mt)
            a[mt] = *(const short8*)(xl + aoff + mt * (16 * XSTRIDE));
        __builtin_amdgcn_s_setprio(1);
        #pragma unroll
        for (int mt = 0; mt < 4; ++mt)
            #pragma unroll
            for (int jt = 0; jt < 4; ++jt)
                acc[mt][jt] = __builtin_amdgcn_mfma_f32_16x16x32_bf16(
                    a[mt], b0[jt], acc[mt][jt], 0, 0, 0);
        __builtin_amdgcn_s_setprio(0);
        ck += 32; aoff += 32;
        if (ck >= 400) { ck -= 400; aoff += XSTRIDE - 400; }

        // prefetch ks+2 into b0 (guard final pair)
        if (ks + 2 < 38) {
            #pragma unroll
            for (int jt = 0; jt < 4; ++jt)
                b0[jt] = *(const short8*)(bwv + (jt * 38 + ks + 2) * 512);
        }
        #pragma unroll
        for (int mt = 0; mt < 4; ++mt)
            a[mt] = *(const short8*)(xl + aoff + mt * (16 * XSTRIDE));
        __builtin_amdgcn_s_setprio(1);
        #pragma unroll
        for (int mt = 0; mt < 4; ++mt)
            #pragma unroll
            for (int jt = 0; jt < 4; ++jt)
                acc[mt][jt] = __builtin_amdgcn_mfma_f32_16x16x32_bf16(
                    a[mt], b1[jt], acc[mt][jt], 0, 0, 0);
        __builtin_amdgcn_s_setprio(0);
        ck += 32; aoff += 32;
        if (ck >= 400) { ck -= 400; aoff += XSTRIDE - 400; }
    }

    // ---- pool raw acc over 3 segments (this half's t-range), write ws ----
    const int p1 = epos[2 * n], p2 = epos[2 * n + 1];
    float* pf_out = pfe + (n * 2 + wr) * 1536;
    #pragma unroll
    for (int jt = 0; jt < 4; ++jt) {
        float m0 = -1e30f, m1 = -1e30f, m2 = -1e30f;
        #pragma unroll
        for (int mt = 0; mt < 4; ++mt) {
            #pragma unroll
            for (int r = 0; r < 4; ++r) {
                int gt = r0 + mt * 16 + kq * 4 + r;   // global t (C/D row map)
                float v = acc[mt][jt][r];
                if (gt < LPV) {
                    if (gt <= p1) m0 = fmaxf(m0, v);
                    if (gt >= p1 && gt <= p2) m1 = fmaxf(m1, v);
                    if (gt >= p2) m2 = fmaxf(m2, v);
                }
            }
        }
        // lanes sharing col differ in kq (xor 16, 32): reduce t-coverage
        m0 = fmaxf(m0, __shfl_xor(m0, 16)); m0 = fmaxf(m0, __shfl_xor(m0, 32));
        m1 = fmaxf(m1, __shfl_xor(m1, 16)); m1 = fmaxf(m1, __shfl_xor(m1, 32));
        m2 = fmaxf(m2, __shfl_xor(m2, 16)); m2 = fmaxf(m2, __shfl_xor(m2, 32));
        if (kq == 0) {
            int f = wv * 64 + jt * 16 + col;
            pf_out[3 * f + 0] = m0;    // raw max; tanh after cross-half combine
            pf_out[3 * f + 1] = m1;
            pf_out[3 * f + 2] = m2;
        }
    }
}

// kernel 3: combine t-halves, +bias, tanh, out GEMM. One block per sentence.
// (1024 blocks keeps grid saturated; outwT L2 re-reads ~10us aggregate.)
extern "C" __global__ void __launch_bounds__(256)
pcnn_out(const float* __restrict__ pfe, const float* __restrict__ convb,
         const float* __restrict__ outwT,            // [53][1536] fp32 in ws
         const float* __restrict__ outb, float* __restrict__ out)
{
    __shared__ float feat[1536];
    const int n = blockIdx.x;
    const int tid = threadIdx.x;
    const float* pa = pfe + n * 3072;
    const float* pb = pa + 1536;

    for (int i = tid; i < 1536; i += 256) {
        float v = fmaxf(pa[i], pb[i]);
        // tanh monotonic: max(tanh(x+b)) == tanh(max(x)+b); segs nonempty
        feat[i] = tanhf(v + convb[i / 3]);
    }
    __syncthreads();

    const int lane = tid & 63;
    const int wv   = tid >> 6;     // 0..3
    for (int cc = wv; cc < NC; cc += 4) {
        const float* wrow = outwT + cc * 1536;
        float s = 0.f;
        #pragma unroll 4
        for (int jj = lane; jj < 1536; jj += 64)
            s += feat[jj] * wrow[jj];
        s += __shfl_xor(s, 32); s += __shfl_xor(s, 16);
        s += __shfl_xor(s, 8);  s += __shfl_xor(s, 4);
        s += __shfl_xor(s, 2);  s += __shfl_xor(s, 1);
        if (lane == 0) out[n * 53 + cc] = s + outb[cc];
    }
}

extern "C" void kernel_launch(void* const* d_in, const int* in_sizes, int n_in,
                              void* d_out, int out_size, void* d_ws, size_t ws_size,
                              hipStream_t stream) {
    (void)in_sizes; (void)n_in; (void)ws_size; (void)out_size;
    const int* tokens = (const int*)d_in[0];
    const int* pf1    = (const int*)d_in[1];
    const int* pf2    = (const int*)d_in[2];
    const int* epos   = (const int*)d_in[3];
    const float* wordvec = (const float*)d_in[4];
    const float* pf1e    = (const float*)d_in[5];
    const float* pf2e    = (const float*)d_in[6];
    const float* convw   = (const float*)d_in[7];
    const float* convb   = (const float*)d_in[8];
    const float* outw    = (const float*)d_in[9];
    const float* outb    = (const float*)d_in[10];
    float* out = (float*)d_out;

    unsigned short* convwb2 = (unsigned short*)d_ws;       // 1,245,184 B
    float* outwT = (float*)((char*)d_ws + 1245184);        // 325,632 B
    float* pfe   = (float*)((char*)d_ws + 1570816);        // 1024*2*1536 f = 12.6 MB

    prep<<<dim3(688), dim3(1024), 0, stream>>>(convw, outw, convwb2, outwT);

    const size_t lds_bytes = 56816 + 816;                  // 57,632 B -> 2 blocks/CU
    pcnn_half<<<dim3(2048), dim3(512), lds_bytes, stream>>>(
        tokens, pf1, pf2, epos, wordvec, pf1e, pf2e, convwb2, pfe);

    pcnn_out<<<dim3(1024), dim3(256), 0, stream>>>(pfe, convb, outwT, outb, out);
}